// Round 12
// baseline (311.929 us; speedup 1.0000x reference)
//
#include <hip/hip_runtime.h>
#include <hip/hip_bf16.h>
#include <math.h>

// Problem constants
#define B_   16
#define D_   512
#define T_   2048
#define K_   8
#define C_   1024
#define CH_  64
#define NEL_ (B_ * D_ * T_)        // 16777216
#define QOFF 16777216              // out: [quantized | commit | ppl[8]]

// ws layout
#define WS_HCN   0                          // float[K*C]   32 KB (0.5*||c||^2)
#define WS_CNT   32768                      // int[K*C]     32 KB
#define WS_SSE   65536                      // double       8 B
#define WS_CBS   66048                      // PLAIN bf16 (hi only) image of (-c), 8192 rows * 128 B = 1 MB
// image: row r (= k*1024+c) at WS_CBS + r*128; 16B group s (s=0..7, ch 8s..8s+7,
// negated bf16) at s*16. (No swizzle — R12 reads fragments direct from L2;
// the swizzle only existed for the gload_lds lane-mapping constraint.)

typedef __attribute__((ext_vector_type(8))) short   short8;
typedef __attribute__((ext_vector_type(8))) __bf16  bf16x8;
typedef __attribute__((ext_vector_type(4))) float   f32x4;

__device__ __forceinline__ unsigned short f2bf_rne(float f) {
    unsigned u = __builtin_bit_cast(unsigned, f);
    u = u + 0x7FFFu + ((u >> 16) & 1u);
    return (unsigned short)(u >> 16);
}

// ---------------------------------------------------------------------------
// Prep: PLAIN bf16 (hi-only) image of (-c) + 0.5*||c||^2 + counts/sse zero.
// One thread per 16B group. 65536 threads. (R0-proven logic minus the XOR.)
// ---------------------------------------------------------------------------
__global__ void vq_prep(const float* __restrict__ cb,
                        unsigned char* __restrict__ cbS,
                        float* __restrict__ hcn,
                        int* __restrict__ counts,
                        double* __restrict__ sse) {
    int g   = blockIdx.x * 256 + threadIdx.x;
    if (g < K_ * C_) counts[g] = 0;
    if (g == 0) *sse = 0.0;

    int row = g >> 3;
    int s8  = g & 7;
    const float* src = cb + (size_t)row * CH_;

    short8 val;
#pragma unroll
    for (int j = 0; j < 8; ++j)
        val[j] = (short)f2bf_rne(-src[s8 * 8 + j]);
    *(short8*)(cbS + (size_t)row * 128 + s8 * 16) = val;

    if (s8 == 0) {
        float s = 0.f;
#pragma unroll 8
        for (int ch = 0; ch < CH_; ++ch) {
            float v = src[ch];
            s = fmaf(v, v, s);
        }
        hcn[row] = 0.5f * s;
    }
}

// ---------------------------------------------------------------------------
// Main — LDS-free sweep, fragments direct from L2.
// R11 post-mortem: with 16 waves/CU and few barriers, each wave still idles
// >90% of its life (VALU 29%, MFMA 12%, HBM 14%); barrier-drain arithmetic
// (~2 µs total) cannot explain the ~60 µs stall — the staging pipeline's
// wave-lockstep + 4 waves/SIMD latency coverage is structural. The 128 KB
// k-image is L2-RESIDENT (64 blocks re-read each k-slice), so LDS staging
// buys nothing; direct 16 B global loads are fully pipelineable and delete
// every sweep barrier, gload_lds, ds_read and the lockstep.
//   - 256-thread blocks (4 waves), wave owns 32 t = 2 t-tiles (R2-proven
//     shape) -> grid 2048 = 8 blocks/CU -> 32 waves/CU (8 waves/SIMD).
//   - LDS = 512 B (idx table only). ONE barrier in the whole kernel.
//   - VGPR target <=64 for 8 waves/SIMD (state ~55: bh 16, a 8, md/mc 4).
// Tracker: R9's slim explicit compare-select VERBATIM (no packed-fminf,
// R8 rule); j = sub in [0,64) -> identical lexicographic winner; absmax
// must reproduce 0.6113281 bit-for-bit.
// Epilogues: R2's proven coalesced pattern verbatim.
// ---------------------------------------------------------------------------
__global__ __launch_bounds__(256, 8) void vq_main(
    const float* __restrict__ x,
    const float* __restrict__ cb,
    const unsigned char* __restrict__ cbS,
    const float* __restrict__ hcn,
    float* __restrict__ out,
    int* __restrict__ counts,
    double* __restrict__ sse)
{
    __shared__ int idxS[128];

    const int tid  = threadIdx.x;
    const int lane = tid & 63;
    const int wave = tid >> 6;          // 0..3
    const int ln   = lane & 15;
    const int q    = lane >> 4;
    const int q4   = q * 4;

    const int bid = blockIdx.x;
    const int tc  = bid & 15;           // 16 t-chunks of 128
    const int k   = (bid >> 4) & 7;
    const int b   = bid >> 7;
    const int t0b = tc * 128;           // block's t base
    const int tw  = t0b + wave * 32;    // wave's t base

    // ---- x fragments (queries) + ||x||^2 per query (R2 verbatim) ----
    short8 bh[2][2];    // [tt][kstep]
    float  xn[2];       // ||x_t||^2 for t = tw + tt*16 + ln (all lanes)
#pragma unroll
    for (int tt = 0; tt < 2; ++tt) {
        int t = tw + tt * 16 + ln;
        float pn = 0.f;
#pragma unroll
        for (int ks = 0; ks < 2; ++ks) {
            const float* xp = x + ((size_t)(b * D_ + k * CH_ + ks * 32 + q * 8)) * T_ + t;
            short8 sh;
#pragma unroll
            for (int j = 0; j < 8; ++j) {
                float v = xp[(size_t)j * T_];
                pn = fmaf(v, v, pn);
                sh[j] = (short)f2bf_rne(v);
            }
            bh[tt][ks] = sh;
        }
        pn += __shfl_xor(pn, 16);       // sum the 4 q-lane partials
        pn += __shfl_xor(pn, 32);
        xn[tt] = pn;
    }

    const unsigned char* cbS_k = cbS + (size_t)k * C_ * 128;
    const float*         hcn_k = hcn + k * C_;

    // ---- Barrier-free sweep over all 1024 codes, fragments from L2 ----
    // Slot (tt, r) at sub: code = sub*16 + q4 + r, sub in [0,64).
    float md[2];
    int   mc[2];
#pragma unroll
    for (int tt = 0; tt < 2; ++tt) { md[tt] = INFINITY; mc[tt] = 0; }

#pragma unroll 4
    for (int sub = 0; sub < 64; ++sub) {
        const unsigned char* rowb = cbS_k + (size_t)((sub * 16 + ln) * 128);
        // h = 0.5||c||^2: q-broadcast 16B lines, L1/L2-hot (R11-proven).
        f32x4 h4 = *(const f32x4*)(hcn_k + sub * 16 + q4);
        f32x4 a[2];
        a[0] = h4;
        a[1] = h4;
#pragma unroll
        for (int ks = 0; ks < 2; ++ks) {
            bf16x8 ah = __builtin_bit_cast(bf16x8,
                            *(const short8*)(rowb + (ks * 4 + q) * 16));
#pragma unroll
            for (int tt = 0; tt < 2; ++tt)
                a[tt] = __builtin_amdgcn_mfma_f32_16x16x32_bf16(
                    ah, __builtin_bit_cast(bf16x8, bh[tt][ks]), a[tt], 0, 0, 0);
        }
        const int j4 = sub * 4;
#pragma unroll
        for (int tt = 0; tt < 2; ++tt) {
            // Min-tree + first-match r (smallest r on ties), strict-< on sub
            // (earliest sub on ties) — identical winner to R9/R11.
            float m01 = fminf(a[tt][0], a[tt][1]);
            float m23 = fminf(a[tt][2], a[tt][3]);
            float m   = fminf(m01, m23);
            int rw = (m == a[tt][0]) ? 0 :
                     (m == a[tt][1]) ? 1 :
                     (m == a[tt][2]) ? 2 : 3;
            bool lt = m < md[tt];
            md[tt] = lt ? m : md[tt];
            mc[tt] = lt ? (j4 + rw) : mc[tt];
        }
    }

    // ---- Epilogue A: consensus + SSE + counts + idx publish ----
    double waveSse = 0.0;
#pragma unroll
    for (int tt = 0; tt < 2; ++tt) {
        float d1 = md[tt];
        int   c1 = ((mc[tt] >> 2) << 4) + q4 + (mc[tt] & 3);   // sub*16+q4+r
        // Cross-lane top-1 merge over q (xor 16, 32), lexicographic ->
        // all 4 q-lanes converge bitwise on the same (d1, c1). (R9-proven.)
#pragma unroll
        for (int off = 16; off <= 32; off <<= 1) {
            float ov = __shfl_xor(d1, off);
            int   oc = __shfl_xor(c1, off);
            bool w = (ov < d1) || (ov == d1 && oc < c1);
            d1 = w ? ov : d1;
            c1 = w ? oc : c1;
        }

        if (q == 0) {                        // one vote per query
            // ||x - c||^2 = ||x||^2 + 2*(0.5||c||^2 - x.c) = xn + 2*score
            waveSse += (double)(xn[tt] + 2.0f * d1);
            atomicAdd(&counts[k * C_ + c1], 1);
            idxS[wave * 32 + tt * 16 + ln] = c1;   // idxS[i] = idx for t0b+i
        }
    }

    // One fp64 atomic per wave.
    for (int off = 32; off > 0; off >>= 1) waveSse += __shfl_down(waveSse, off);
    if (lane == 0) atomicAdd(sse, waveSse);

    __syncthreads();   // idx table visible to all waves (the ONLY barrier)

    // ---- Epilogue B: coalesced quantized write (R2 verbatim) ----
    // Wave owns 16 ch rows (ch = wave*16 + 4p + jj); lane l covers t = t0b+2l,
    // t0b+2l+1. Gather the lane's two codebook row-slices (4 x f32x4 each,
    // L2-hot), emit float2 stores: 512 B fully-contiguous per wave-instr.
    const float* cb_k = cb + (size_t)k * C_ * CH_;
    const int i0 = idxS[2 * lane];
    const int i1 = idxS[2 * lane + 1];
    const float* r0 = cb_k + (size_t)i0 * CH_ + wave * 16;
    const float* r1 = cb_k + (size_t)i1 * CH_ + wave * 16;
#pragma unroll
    for (int p = 0; p < 4; ++p) {
        f32x4 a0 = *(const f32x4*)(r0 + 4 * p);
        f32x4 a1 = *(const f32x4*)(r1 + 4 * p);
#pragma unroll
        for (int jj = 0; jj < 4; ++jj) {
            int ch = wave * 16 + 4 * p + jj;
            float2 v = make_float2(a0[jj], a1[jj]);
            *(float2*)(out + ((size_t)(b * D_ + k * CH_ + ch)) * T_
                           + t0b + 2 * lane) = v;
        }
    }
}

// ---------------------------------------------------------------------------
// Finalize: one block per k -> perplexity; block 0 also writes commit loss.
// ---------------------------------------------------------------------------
__global__ void vq_final(const int* __restrict__ counts,
                         const double* __restrict__ sse,
                         float* __restrict__ out) {
    __shared__ double part[4];
    const int tid = threadIdx.x;
    const int k   = blockIdx.x;
    double local = 0.0;
    for (int j = tid; j < C_; j += 256) {
        double p = (double)counts[k * C_ + j] * (1.0 / (double)(B_ * T_));
        local += -p * log(p + 1e-8);
    }
    for (int off = 32; off > 0; off >>= 1) local += __shfl_down(local, off);
    if ((tid & 63) == 0) part[tid >> 6] = local;
    __syncthreads();
    if (tid == 0) {
        double sum = part[0] + part[1] + part[2] + part[3];
        out[QOFF + 1 + k] = (float)exp(sum);
        if (k == 0)
            out[QOFF] = (float)(1.25 * (*sse) / (double)NEL_);
    }
}

// ---------------------------------------------------------------------------
extern "C" void kernel_launch(void* const* d_in, const int* in_sizes, int n_in,
                              void* d_out, int out_size, void* d_ws, size_t ws_size,
                              hipStream_t stream) {
    const float* x  = (const float*)d_in[0];
    const float* cb = (const float*)d_in[1];
    float* out = (float*)d_out;

    float*         hcn    = (float*)((char*)d_ws + WS_HCN);
    int*           counts = (int*)((char*)d_ws + WS_CNT);
    double*        sse    = (double*)((char*)d_ws + WS_SSE);
    unsigned char* cbS    = (unsigned char*)((char*)d_ws + WS_CBS);

    vq_prep<<<(K_ * C_ * 8) / 256, 256, 0, stream>>>(cb, cbS, hcn, counts, sse);
    vq_main<<<B_ * K_ * (T_ / 128), 256, 0, stream>>>(x, cb, cbS, hcn,
                                                      out, counts, sse);
    vq_final<<<K_, 256, 0, stream>>>(counts, sse, out);
}